// Round 5
// baseline (736.636 us; speedup 1.0000x reference)
//
#include <hip/hip_runtime.h>
#include <cfloat>

// Geometry: z (32,256,32,32) f32, W (1024,256) f32.
// P = 32768 (p = n*1024+hw), K = 256, CODES = 1024.
// d_out = [quantized 8388608][straight_through 8388608][indices-as-float 32768]
// Strategy: bf16 MFMA screen (candidates within EPS of min) + exact fp32
// rescore (bitwise-identical to the validated R1/R3 arithmetic), with
// full-scan fallback on candidate overflow.

#define P_TOTAL   32768
#define N_CODES   1024
#define Q_ELEMS   8388608
#define EPS_SCREEN 1.0e-2f   // rigorous bf16-screen bound is ~2.3e-3; 4x margin
#define CAND_CAP  64

typedef __attribute__((ext_vector_type(8))) short bf16x8;
typedef __attribute__((ext_vector_type(4))) float f32x4;

#define GLOAD16(gsrc, ldst) \
  __builtin_amdgcn_global_load_lds((const __attribute__((address_space(1))) void*)(gsrc), \
                                   (__attribute__((address_space(3))) void*)(ldst), 16, 0, 0)

__device__ __forceinline__ unsigned short f2bf(float f) {   // RN-even f32->bf16
    unsigned u = __builtin_bit_cast(unsigned, f);
    u += 0x7FFF + ((u >> 16) & 1);
    return (unsigned short)(u >> 16);
}

__device__ __forceinline__ float sq_sep(float v) {
    float t = v * v;
    asm volatile("" : "+v"(t));
    return t;
}

// ---------------------------------------------------------------------------
// k0w: W[1024][256] f32 -> W_hi bf16; 16B granules XOR-swizzled in each 512B
// row: granule g of code c stored at slot g^(c&7)  (conflict-light frag reads
// in k2s after linear global_load_lds staging).
// ---------------------------------------------------------------------------
__global__ void k0w_pack(const float* __restrict__ wemb, unsigned short* __restrict__ whi) {
    const int t = blockIdx.x * 256 + threadIdx.x;   // 32768 granules
    const int c = t >> 5, g = t & 31;
    const float4 v0 = *(const float4*)&wemb[(size_t)c * 256 + g * 8];
    const float4 v1 = *(const float4*)&wemb[(size_t)c * 256 + g * 8 + 4];
    bf16x8 hv;
    hv[0] = (short)f2bf(v0.x); hv[1] = (short)f2bf(v0.y);
    hv[2] = (short)f2bf(v0.z); hv[3] = (short)f2bf(v0.w);
    hv[4] = (short)f2bf(v1.x); hv[5] = (short)f2bf(v1.y);
    hv[6] = (short)f2bf(v1.z); hv[7] = (short)f2bf(v1.w);
    const int gs = g ^ (c & 7);
    *(bf16x8*)(whi + (size_t)c * 256 + gs * 8) = hv;
}

// ---------------------------------------------------------------------------
// k0z: z [n][k][hw] f32 -> z_hi [p][k] bf16 (transpose via LDS). grid 512.
// ---------------------------------------------------------------------------
#define T16S 280   // ushort stride: 560B rows (16B aligned)
__global__ void k0z_pack(const float* __restrict__ z, unsigned short* __restrict__ zhi) {
    __shared__ unsigned short t16[64 * T16S];   // 35,840 B
    const int tid = threadIdx.x;
    const int n = blockIdx.x >> 4, hc = blockIdx.x & 15;
    const int hw0 = hc * 64;
    const int w = tid >> 6, hl = tid & 63;
    #pragma unroll
    for (int i = 0; i < 64; ++i) {
        const int k = i * 4 + w;
        const float v = z[((size_t)(n * 256 + k) << 10) + hw0 + hl];
        t16[hl * T16S + k] = f2bf(v);
    }
    __syncthreads();
    const int row = tid >> 2, cp = tid & 3;
    const size_t p0 = (size_t)(n * 1024 + hw0);
    #pragma unroll
    for (int i = 0; i < 8; ++i) {
        const int chunk = i * 4 + cp;
        *(bf16x8*)(zhi + (p0 + row) * 256 + chunk * 8) =
            *(const bf16x8*)&t16[row * T16S + chunk * 8];
    }
}

// ---------------------------------------------------------------------------
// k1: zsq[p] / wsq[c], numpy pairwise order (128+128, 8 accumulators).
// UNCHANGED from the validated R1/R3 kernel.
// ---------------------------------------------------------------------------
__global__ void k1_sums(const float* __restrict__ z, const float* __restrict__ wemb,
                        float* __restrict__ zsq, float* __restrict__ wsq) {
    const int b = blockIdx.x;
    const int tid = threadIdx.x;
    if (b < 128) {
        const int p = b * 256 + tid;
        const int n = p >> 10, hw = p & 1023;
        const float* base = z + (((size_t)(n * 256)) << 10) + hw;
        float half[2];
        #pragma unroll
        for (int h = 0; h < 2; ++h) {
            const float* x = base + (((size_t)(h * 128)) << 10);
            float r[8];
            #pragma unroll
            for (int j = 0; j < 8; ++j) r[j] = sq_sep(x[((size_t)j) << 10]);
            for (int i = 8; i < 128; i += 8) {
                #pragma unroll
                for (int j = 0; j < 8; ++j) r[j] += sq_sep(x[((size_t)(i + j)) << 10]);
            }
            half[h] = ((r[0] + r[1]) + (r[2] + r[3])) + ((r[4] + r[5]) + (r[6] + r[7]));
        }
        zsq[p] = half[0] + half[1];
    } else {
        const int c = (b - 128) * 256 + tid;
        const float* base = wemb + (size_t)c * 256;
        float half[2];
        #pragma unroll
        for (int h = 0; h < 2; ++h) {
            const float* x = base + h * 128;
            float r[8];
            #pragma unroll
            for (int j = 0; j < 8; ++j) r[j] = sq_sep(x[j]);
            for (int i = 8; i < 128; i += 8) {
                #pragma unroll
                for (int j = 0; j < 8; ++j) r[j] += sq_sep(x[i + j]);
            }
            half[h] = ((r[0] + r[1]) + (r[2] + r[3])) + ((r[4] + r[5]) + (r[6] + r[7]));
        }
        wsq[c] = half[0] + half[1];
    }
}

// ---------------------------------------------------------------------------
// k2s: bf16 MFMA screen. Block = 64 pos (4 waves x 16), grid 512.
// Codes in 32 chunks of 32; Bs double-buffered (2x16KB), staged via
// global_load_lds (linear; swizzle pre-baked in W_hi). Per (pos,chunk):
// d_a = fma(-2, dot_hh, wsq); collect codes with d_a <= running_min + EPS.
// A-frag: lane la=l&15 -> row, slot j of group kg=l>>4 -> k=ks*32+kg*8+j.
// C/D (m89): col=l&15, row=kg*4+reg.
// LDS total: 32 KB + 256 B  (< 64 KB workgroup limit — R4's 66 KB failed launch).
// ---------------------------------------------------------------------------
__launch_bounds__(256, 1)
__global__ void k2s_screen(const unsigned short* __restrict__ zhi,
                           const unsigned short* __restrict__ whi,
                           const float* __restrict__ wsq,
                           unsigned short* __restrict__ candC,
                           int* __restrict__ candCnt) {
    __shared__ unsigned short Bs[2][32 * 256];   // 16 KB x2
    __shared__ int cnt[64];
    const int tid = threadIdx.x, bid = blockIdx.x;
    const int w = tid >> 6, l = tid & 63;
    const int la = l & 15, kg = l >> 4;
    const int m0 = bid * 64 + w * 16;
    if (tid < 64) cnt[tid] = 0;

    bf16x8 af[8];
    #pragma unroll
    for (int ks = 0; ks < 8; ++ks)
        af[ks] = *(const bf16x8*)(zhi + (size_t)(m0 + la) * 256 + ks * 32 + kg * 8);

    float rg[4];
    #pragma unroll
    for (int r = 0; r < 4; ++r) rg[r] = FLT_MAX;

#define STAGEB(buf, cb_) do {                                                  \
    const unsigned short* src_ = whi + (size_t)(cb_) * 256;                    \
    _Pragma("unroll")                                                          \
    for (int i_ = 0; i_ < 4; ++i_)                                             \
        GLOAD16(src_ + i_ * 2048 + tid * 8, &Bs[buf][i_ * 2048 + tid * 8]);    \
} while (0)

    STAGEB(0, 0);
    __syncthreads();                      // cnt ready + Bs[0] landed

    for (int ch = 0; ch < 32; ++ch) {
        const int cur = ch & 1;
        const int cb = ch * 32;
        if (ch < 31) STAGEB(cur ^ 1, cb + 32);

        float wsqv[2];
        #pragma unroll
        for (int nf = 0; nf < 2; ++nf) wsqv[nf] = wsq[cb + nf * 16 + la];

        f32x4 acc[2];
        #pragma unroll
        for (int nf = 0; nf < 2; ++nf) acc[nf] = (f32x4){0.f, 0.f, 0.f, 0.f};

        #pragma unroll
        for (int ks = 0; ks < 8; ++ks) {
            bf16x8 bfv[2];
            #pragma unroll
            for (int nf = 0; nf < 2; ++nf) {
                const int cl = nf * 16 + la;
                const int slot = (ks * 4 + kg) ^ (cl & 7);   // un-swizzle
                bfv[nf] = *(const bf16x8*)&Bs[cur][cl * 256 + slot * 8];
            }
            #pragma unroll
            for (int nf = 0; nf < 2; ++nf)
                acc[nf] = __builtin_amdgcn_mfma_f32_16x16x32_bf16(
                    af[ks], bfv[nf], acc[nf], 0, 0, 0);
        }

        float da[2][4];
        #pragma unroll
        for (int nf = 0; nf < 2; ++nf)
            #pragma unroll
            for (int r = 0; r < 4; ++r)
                da[nf][r] = __builtin_fmaf(-2.f, acc[nf][r], wsqv[nf]);

        #pragma unroll
        for (int r = 0; r < 4; ++r) {
            float mv = fminf(da[0][r], da[1][r]);
            #pragma unroll
            for (int off = 1; off < 16; off <<= 1)
                mv = fminf(mv, __shfl_xor(mv, off));
            rg[r] = fminf(rg[r], mv);
        }

        #pragma unroll
        for (int nf = 0; nf < 2; ++nf)
            #pragma unroll
            for (int r = 0; r < 4; ++r)
                if (da[nf][r] <= rg[r] + EPS_SCREEN) {
                    const int plocal = w * 16 + kg * 4 + r;
                    const int slot = atomicAdd(&cnt[plocal], 1);
                    if (slot < CAND_CAP)
                        candC[(size_t)(bid * 64 + plocal) * CAND_CAP + slot] =
                            (unsigned short)(cb + nf * 16 + la);
                }

        __syncthreads();   // Bs[cur] reads done; Bs[cur^1] landed (vmcnt(0))
    }
#undef STAGEB

    if (tid < 64) candCnt[bid * 64 + tid] = cnt[tid];   // raw (overflow detectable)
}

// ---------------------------------------------------------------------------
// k2r: exact rescore. Bitwise-identical arithmetic to validated R1/R3:
// sequential k-ascending fp32 fma dot, d = fma(-2,dot,zsq)+wsq, (d,c) lex min.
// Overflowed positions (cnt > CAND_CAP) fall back to full 1024-code scan.
// ---------------------------------------------------------------------------
__global__ void k2r_rescore(const float* __restrict__ z, const float* __restrict__ wemb,
                            const float* __restrict__ zsq, const float* __restrict__ wsq,
                            const unsigned short* __restrict__ candC,
                            const int* __restrict__ candCnt,
                            float* __restrict__ idx_out) {
    const int p = blockIdx.x * 256 + threadIdx.x;
    const int n = p >> 10, hw = p & 1023;
    const float* zb = z + (((size_t)(n * 256)) << 10) + hw;
    const float zsv = zsq[p];
    const int count = candCnt[p];
    float bd = FLT_MAX;
    int bc = N_CODES;
    if (count <= CAND_CAP) {
        for (int s = 0; s < count; ++s) {
            const int c = candC[(size_t)p * CAND_CAP + s];
            const float* wb = wemb + (size_t)c * 256;
            float dot = 0.f;
            #pragma unroll 8
            for (int k = 0; k < 256; ++k)
                dot = __builtin_fmaf(zb[(size_t)k << 10], wb[k], dot);
            const float d = __builtin_fmaf(-2.f, dot, zsv) + wsq[c];
            if (d < bd || (d == bd && c < bc)) { bd = d; bc = c; }
        }
    } else {
        for (int c = 0; c < N_CODES; ++c) {
            const float* wb = wemb + (size_t)c * 256;
            float dot = 0.f;
            #pragma unroll 8
            for (int k = 0; k < 256; ++k)
                dot = __builtin_fmaf(zb[(size_t)k << 10], wb[k], dot);
            const float d = __builtin_fmaf(-2.f, dot, zsv) + wsq[c];
            if (d < bd) { bd = d; bc = c; }   // strict <: first occurrence
        }
    }
    idx_out[p] = (float)bc;
}

// ---------------------------------------------------------------------------
// k3: gather + straight-through, NCHW float4 writes
// ---------------------------------------------------------------------------
__global__ void k3_gather(const float* __restrict__ z, const float* __restrict__ wemb,
                          const float* __restrict__ idxf,
                          float* __restrict__ out0, float* __restrict__ out1) {
    const int t = blockIdx.x * 256 + threadIdx.x;
    const int hw4 = t & 255, c = (t >> 8) & 255, n = t >> 16;
    const size_t zo = (((size_t)(n * 256 + c)) << 10) + hw4 * 4;
    const float4 zv = *(const float4*)&z[zo];
    const float4 iv = *(const float4*)&idxf[n * 1024 + hw4 * 4];
    float4 qv, st;
    {
        const int i0 = (int)iv.x; qv.x = wemb[(size_t)i0 * 256 + c]; st.x = (qv.x - zv.x) + zv.x;
        const int i1 = (int)iv.y; qv.y = wemb[(size_t)i1 * 256 + c]; st.y = (qv.y - zv.y) + zv.y;
        const int i2 = (int)iv.z; qv.z = wemb[(size_t)i2 * 256 + c]; st.z = (qv.z - zv.z) + zv.z;
        const int i3 = (int)iv.w; qv.w = wemb[(size_t)i3 * 256 + c]; st.w = (qv.w - zv.w) + zv.w;
    }
    *(float4*)&out0[zo] = qv;
    *(float4*)&out1[zo] = st;
}

extern "C" void kernel_launch(void* const* d_in, const int* in_sizes, int n_in,
                              void* d_out, int out_size, void* d_ws, size_t ws_size,
                              hipStream_t stream) {
    const float* z = (const float*)d_in[0];
    const float* wemb = (const float*)d_in[1];
    float* out = (float*)d_out;
    float* out0 = out;                       // quantized (final)
    float* out1 = out + Q_ELEMS;             // straight_through (final)
    float* oidx = out + 2 * Q_ELEMS;         // indices-as-float (final)
    // big scratch inside d_out (all consumed before k3 overwrites):
    unsigned short* zhi = (unsigned short*)out0;                  // 16 MB  (out0[0..4M) floats)
    unsigned short* candC = (unsigned short*)(out0 + 4194304);    // 4 MB   (out0[4M..5.25M))
    int* candCnt = (int*)(out0 + 5242880);                        // 128 KB (out0[5.25M..5.28M))
    unsigned short* whi = (unsigned short*)out1;                  // 512 KB (out1 head)
    // d_ws scratch (135 KB, well under proven capacity):
    float* ws = (float*)d_ws;
    float* zsq = ws;                          // 32768 f32
    float* wsq = ws + 32768;                  // 1024 f32

    k0w_pack<<<128, 256, 0, stream>>>(wemb, whi);
    k0z_pack<<<512, 256, 0, stream>>>(z, zhi);
    k1_sums<<<132, 256, 0, stream>>>(z, wemb, zsq, wsq);
    k2s_screen<<<512, 256, 0, stream>>>(zhi, whi, wsq, candC, candCnt);
    k2r_rescore<<<128, 256, 0, stream>>>(z, wemb, zsq, wsq, candC, candCnt, oidx);
    k3_gather<<<Q_ELEMS / 4 / 256, 256, 0, stream>>>(z, wemb, oidx, out0, out1);
}

// Round 6
// 308.928 us; speedup vs baseline: 2.3845x; 2.3845x over previous
//
#include <hip/hip_runtime.h>
#include <cfloat>

// Geometry: z (32,256,32,32) f32, W (1024,256) f32.
// P = 32768 (p = n*1024+hw), K = 256, CODES = 1024.
// d_out = [quantized 8388608][straight_through 8388608][indices-as-float 32768]
// Strategy: bf16 MFMA screen (candidates within EPS of min) + exact fp32
// rescore (bitwise-identical chain), wave-per-position rescore.

#define P_TOTAL   32768
#define N_CODES   1024
#define Q_ELEMS   8388608
#define EPS_SCREEN 1.0e-2f   // rigorous bf16-screen bound is ~2.3e-3; 4x margin
#define CAND_CAP  64

typedef __attribute__((ext_vector_type(8))) short bf16x8;
typedef __attribute__((ext_vector_type(4))) float f32x4;

#define GLOAD16(gsrc, ldst) \
  __builtin_amdgcn_global_load_lds((const __attribute__((address_space(1))) void*)(gsrc), \
                                   (__attribute__((address_space(3))) void*)(ldst), 16, 0, 0)

__device__ __forceinline__ unsigned short f2bf(float f) {   // RN-even f32->bf16
    unsigned u = __builtin_bit_cast(unsigned, f);
    u += 0x7FFF + ((u >> 16) & 1);
    return (unsigned short)(u >> 16);
}

__device__ __forceinline__ float sq_sep(float v) {
    float t = v * v;
    asm volatile("" : "+v"(t));
    return t;
}

// ---------------------------------------------------------------------------
// k0w: W[1024][256] f32 -> W_hi bf16; 16B granules XOR-swizzled in each 512B
// row: granule g of code c stored at slot g^(c&7).
// ---------------------------------------------------------------------------
__global__ void k0w_pack(const float* __restrict__ wemb, unsigned short* __restrict__ whi) {
    const int t = blockIdx.x * 256 + threadIdx.x;   // 32768 granules
    const int c = t >> 5, g = t & 31;
    const float4 v0 = *(const float4*)&wemb[(size_t)c * 256 + g * 8];
    const float4 v1 = *(const float4*)&wemb[(size_t)c * 256 + g * 8 + 4];
    bf16x8 hv;
    hv[0] = (short)f2bf(v0.x); hv[1] = (short)f2bf(v0.y);
    hv[2] = (short)f2bf(v0.z); hv[3] = (short)f2bf(v0.w);
    hv[4] = (short)f2bf(v1.x); hv[5] = (short)f2bf(v1.y);
    hv[6] = (short)f2bf(v1.z); hv[7] = (short)f2bf(v1.w);
    const int gs = g ^ (c & 7);
    *(bf16x8*)(whi + (size_t)c * 256 + gs * 8) = hv;
}

// ---------------------------------------------------------------------------
// k0z: z [n][k][hw] f32 -> z_hi [p][k] bf16 (transpose via LDS). grid 512.
// ---------------------------------------------------------------------------
#define T16S 280   // ushort stride: 560B rows (16B aligned)
__global__ void k0z_pack(const float* __restrict__ z, unsigned short* __restrict__ zhi) {
    __shared__ unsigned short t16[64 * T16S];   // 35,840 B
    const int tid = threadIdx.x;
    const int n = blockIdx.x >> 4, hc = blockIdx.x & 15;
    const int hw0 = hc * 64;
    const int w = tid >> 6, hl = tid & 63;
    #pragma unroll
    for (int i = 0; i < 64; ++i) {
        const int k = i * 4 + w;
        const float v = z[((size_t)(n * 256 + k) << 10) + hw0 + hl];
        t16[hl * T16S + k] = f2bf(v);
    }
    __syncthreads();
    const int row = tid >> 2, cp = tid & 3;
    const size_t p0 = (size_t)(n * 1024 + hw0);
    #pragma unroll
    for (int i = 0; i < 8; ++i) {
        const int chunk = i * 4 + cp;
        *(bf16x8*)(zhi + (p0 + row) * 256 + chunk * 8) =
            *(const bf16x8*)&t16[row * T16S + chunk * 8];
    }
}

// ---------------------------------------------------------------------------
// k1: zsq[p] / wsq[c], numpy pairwise order (128+128, 8 accumulators).
// UNCHANGED from the validated R1/R3/R5 kernel.
// ---------------------------------------------------------------------------
__global__ void k1_sums(const float* __restrict__ z, const float* __restrict__ wemb,
                        float* __restrict__ zsq, float* __restrict__ wsq) {
    const int b = blockIdx.x;
    const int tid = threadIdx.x;
    if (b < 128) {
        const int p = b * 256 + tid;
        const int n = p >> 10, hw = p & 1023;
        const float* base = z + (((size_t)(n * 256)) << 10) + hw;
        float half[2];
        #pragma unroll
        for (int h = 0; h < 2; ++h) {
            const float* x = base + (((size_t)(h * 128)) << 10);
            float r[8];
            #pragma unroll
            for (int j = 0; j < 8; ++j) r[j] = sq_sep(x[((size_t)j) << 10]);
            for (int i = 8; i < 128; i += 8) {
                #pragma unroll
                for (int j = 0; j < 8; ++j) r[j] += sq_sep(x[((size_t)(i + j)) << 10]);
            }
            half[h] = ((r[0] + r[1]) + (r[2] + r[3])) + ((r[4] + r[5]) + (r[6] + r[7]));
        }
        zsq[p] = half[0] + half[1];
    } else {
        const int c = (b - 128) * 256 + tid;
        const float* base = wemb + (size_t)c * 256;
        float half[2];
        #pragma unroll
        for (int h = 0; h < 2; ++h) {
            const float* x = base + h * 128;
            float r[8];
            #pragma unroll
            for (int j = 0; j < 8; ++j) r[j] = sq_sep(x[j]);
            for (int i = 8; i < 128; i += 8) {
                #pragma unroll
                for (int j = 0; j < 8; ++j) r[j] += sq_sep(x[i + j]);
            }
            half[h] = ((r[0] + r[1]) + (r[2] + r[3])) + ((r[4] + r[5]) + (r[6] + r[7]));
        }
        wsq[c] = half[0] + half[1];
    }
}

// ---------------------------------------------------------------------------
// k2s: bf16 MFMA screen. Block = 64 pos (4 waves x 16), grid 512.
// UNCHANGED from validated R5.
// ---------------------------------------------------------------------------
__launch_bounds__(256, 1)
__global__ void k2s_screen(const unsigned short* __restrict__ zhi,
                           const unsigned short* __restrict__ whi,
                           const float* __restrict__ wsq,
                           unsigned short* __restrict__ candC,
                           int* __restrict__ candCnt) {
    __shared__ unsigned short Bs[2][32 * 256];   // 16 KB x2
    __shared__ int cnt[64];
    const int tid = threadIdx.x, bid = blockIdx.x;
    const int w = tid >> 6, l = tid & 63;
    const int la = l & 15, kg = l >> 4;
    const int m0 = bid * 64 + w * 16;
    if (tid < 64) cnt[tid] = 0;

    bf16x8 af[8];
    #pragma unroll
    for (int ks = 0; ks < 8; ++ks)
        af[ks] = *(const bf16x8*)(zhi + (size_t)(m0 + la) * 256 + ks * 32 + kg * 8);

    float rg[4];
    #pragma unroll
    for (int r = 0; r < 4; ++r) rg[r] = FLT_MAX;

#define STAGEB(buf, cb_) do {                                                  \
    const unsigned short* src_ = whi + (size_t)(cb_) * 256;                    \
    _Pragma("unroll")                                                          \
    for (int i_ = 0; i_ < 4; ++i_)                                             \
        GLOAD16(src_ + i_ * 2048 + tid * 8, &Bs[buf][i_ * 2048 + tid * 8]);    \
} while (0)

    STAGEB(0, 0);
    __syncthreads();                      // cnt ready + Bs[0] landed

    for (int ch = 0; ch < 32; ++ch) {
        const int cur = ch & 1;
        const int cb = ch * 32;
        if (ch < 31) STAGEB(cur ^ 1, cb + 32);

        float wsqv[2];
        #pragma unroll
        for (int nf = 0; nf < 2; ++nf) wsqv[nf] = wsq[cb + nf * 16 + la];

        f32x4 acc[2];
        #pragma unroll
        for (int nf = 0; nf < 2; ++nf) acc[nf] = (f32x4){0.f, 0.f, 0.f, 0.f};

        #pragma unroll
        for (int ks = 0; ks < 8; ++ks) {
            bf16x8 bfv[2];
            #pragma unroll
            for (int nf = 0; nf < 2; ++nf) {
                const int cl = nf * 16 + la;
                const int slot = (ks * 4 + kg) ^ (cl & 7);   // un-swizzle
                bfv[nf] = *(const bf16x8*)&Bs[cur][cl * 256 + slot * 8];
            }
            #pragma unroll
            for (int nf = 0; nf < 2; ++nf)
                acc[nf] = __builtin_amdgcn_mfma_f32_16x16x32_bf16(
                    af[ks], bfv[nf], acc[nf], 0, 0, 0);
        }

        float da[2][4];
        #pragma unroll
        for (int nf = 0; nf < 2; ++nf)
            #pragma unroll
            for (int r = 0; r < 4; ++r)
                da[nf][r] = __builtin_fmaf(-2.f, acc[nf][r], wsqv[nf]);

        #pragma unroll
        for (int r = 0; r < 4; ++r) {
            float mv = fminf(da[0][r], da[1][r]);
            #pragma unroll
            for (int off = 1; off < 16; off <<= 1)
                mv = fminf(mv, __shfl_xor(mv, off));
            rg[r] = fminf(rg[r], mv);
        }

        #pragma unroll
        for (int nf = 0; nf < 2; ++nf)
            #pragma unroll
            for (int r = 0; r < 4; ++r)
                if (da[nf][r] <= rg[r] + EPS_SCREEN) {
                    const int plocal = w * 16 + kg * 4 + r;
                    const int slot = atomicAdd(&cnt[plocal], 1);
                    if (slot < CAND_CAP)
                        candC[(size_t)(bid * 64 + plocal) * CAND_CAP + slot] =
                            (unsigned short)(cb + nf * 16 + la);
                }

        __syncthreads();   // Bs[cur] reads done; Bs[cur^1] landed (vmcnt(0))
    }
#undef STAGEB

    if (tid < 64) candCnt[bid * 64 + tid] = cnt[tid];   // raw (overflow detectable)
}

// ---------------------------------------------------------------------------
// k2r: exact rescore, WAVE PER POSITION. Arithmetic bitwise-identical to the
// validated R5 rescore: per-candidate sequential k-ascending fp32 fma dot on
// the same values (z-row broadcast from LDS), d = fma(-2,dot,zsq)+wsq,
// lex-min (d,c) == first-occurrence/lowest-index tie-break.
// Lane j rescores candidate j; count>CAP falls back to full 1024-code sweep.
// ---------------------------------------------------------------------------
__launch_bounds__(256, 8)
__global__ void k2r_rescore(const float* __restrict__ z, const float* __restrict__ wemb,
                            const float* __restrict__ zsq, const float* __restrict__ wsq,
                            const unsigned short* __restrict__ candC,
                            const int* __restrict__ candCnt,
                            float* __restrict__ idx_out) {
    __shared__ float zf[4][256];
    const int tid = threadIdx.x;
    const int wv = tid >> 6, l = tid & 63;
    const int p = blockIdx.x * 4 + wv;
    const int n = p >> 10, hw = p & 1023;
    const float* zb = z + (((size_t)(n * 256)) << 10) + hw;

    // stage this wave's z row (k ascending) into LDS
    #pragma unroll
    for (int j = 0; j < 4; ++j)
        zf[wv][l * 4 + j] = zb[(size_t)(l * 4 + j) << 10];
    __syncthreads();

    const float zsv = zsq[p];
    const int count = candCnt[p];
    const float* zrow = zf[wv];
    float bd = FLT_MAX;
    int bc = N_CODES;

    if (count <= CAND_CAP) {
        if (l < count) {
            const int c = candC[(size_t)p * CAND_CAP + l];
            const float* wb = wemb + (size_t)c * 256;
            float dot = 0.f;
            #pragma unroll 8
            for (int k = 0; k < 256; ++k)
                dot = __builtin_fmaf(zrow[k], wb[k], dot);
            bd = __builtin_fmaf(-2.f, dot, zsv) + wsq[c];
            bc = c;
        }
    } else {
        for (int r = 0; r < 16; ++r) {
            const int c = r * 64 + l;
            const float* wb = wemb + (size_t)c * 256;
            float dot = 0.f;
            #pragma unroll 8
            for (int k = 0; k < 256; ++k)
                dot = __builtin_fmaf(zrow[k], wb[k], dot);
            const float d = __builtin_fmaf(-2.f, dot, zsv) + wsq[c];
            if (d < bd || (d == bd && c < bc)) { bd = d; bc = c; }
        }
    }

    // lex-min (d, c) across the 64 lanes
    #pragma unroll
    for (int off = 1; off < 64; off <<= 1) {
        const float od = __shfl_xor(bd, off);
        const int   oi = __shfl_xor(bc, off);
        if (od < bd || (od == bd && oi < bc)) { bd = od; bc = oi; }
    }
    if (l == 0) idx_out[p] = (float)bc;
}

// ---------------------------------------------------------------------------
// k3: gather + straight-through, NCHW float4 writes
// ---------------------------------------------------------------------------
__global__ void k3_gather(const float* __restrict__ z, const float* __restrict__ wemb,
                          const float* __restrict__ idxf,
                          float* __restrict__ out0, float* __restrict__ out1) {
    const int t = blockIdx.x * 256 + threadIdx.x;
    const int hw4 = t & 255, c = (t >> 8) & 255, n = t >> 16;
    const size_t zo = (((size_t)(n * 256 + c)) << 10) + hw4 * 4;
    const float4 zv = *(const float4*)&z[zo];
    const float4 iv = *(const float4*)&idxf[n * 1024 + hw4 * 4];
    float4 qv, st;
    {
        const int i0 = (int)iv.x; qv.x = wemb[(size_t)i0 * 256 + c]; st.x = (qv.x - zv.x) + zv.x;
        const int i1 = (int)iv.y; qv.y = wemb[(size_t)i1 * 256 + c]; st.y = (qv.y - zv.y) + zv.y;
        const int i2 = (int)iv.z; qv.z = wemb[(size_t)i2 * 256 + c]; st.z = (qv.z - zv.z) + zv.z;
        const int i3 = (int)iv.w; qv.w = wemb[(size_t)i3 * 256 + c]; st.w = (qv.w - zv.w) + zv.w;
    }
    *(float4*)&out0[zo] = qv;
    *(float4*)&out1[zo] = st;
}

extern "C" void kernel_launch(void* const* d_in, const int* in_sizes, int n_in,
                              void* d_out, int out_size, void* d_ws, size_t ws_size,
                              hipStream_t stream) {
    const float* z = (const float*)d_in[0];
    const float* wemb = (const float*)d_in[1];
    float* out = (float*)d_out;
    float* out0 = out;                       // quantized (final)
    float* out1 = out + Q_ELEMS;             // straight_through (final)
    float* oidx = out + 2 * Q_ELEMS;         // indices-as-float (final)
    // big scratch inside d_out (all consumed before k3 overwrites):
    unsigned short* zhi = (unsigned short*)out0;                  // 16 MB
    unsigned short* candC = (unsigned short*)(out0 + 4194304);    // 4 MB
    int* candCnt = (int*)(out0 + 5242880);                        // 128 KB
    unsigned short* whi = (unsigned short*)out1;                  // 512 KB
    // d_ws scratch:
    float* ws = (float*)d_ws;
    float* zsq = ws;                          // 32768 f32
    float* wsq = ws + 32768;                  // 1024 f32

    k0w_pack<<<128, 256, 0, stream>>>(wemb, whi);
    k0z_pack<<<512, 256, 0, stream>>>(z, zhi);
    k1_sums<<<132, 256, 0, stream>>>(z, wemb, zsq, wsq);
    k2s_screen<<<512, 256, 0, stream>>>(zhi, whi, wsq, candC, candCnt);
    k2r_rescore<<<P_TOTAL / 4, 256, 0, stream>>>(z, wemb, zsq, wsq, candC, candCnt, oidx);
    k3_gather<<<Q_ELEMS / 4 / 256, 256, 0, stream>>>(z, wemb, oidx, out0, out1);
}